// Round 15
// baseline (124.246 us; speedup 1.0000x reference)
//
#include <hip/hip_runtime.h>
#include <hip/hip_bf16.h>
#include <math.h>

typedef __bf16 bf16;
typedef __attribute__((ext_vector_type(8))) __bf16 bf16x8;
typedef __attribute__((ext_vector_type(4))) __bf16 bf16x4;
typedef __attribute__((ext_vector_type(2))) __bf16 bf16x2;
typedef __attribute__((ext_vector_type(4))) float f32x4;
typedef __attribute__((ext_vector_type(16))) float f32x16;
typedef __attribute__((ext_vector_type(4))) unsigned u32x4;

#define MFMA(a,b,c)   __builtin_amdgcn_mfma_f32_16x16x32_bf16(a,b,c,0,0,0)
#define MFMA32(a,b,c) __builtin_amdgcn_mfma_f32_32x32x16_bf16(a,b,c,0,0,0)

static constexpr int Bb = 4, Nn = 2048, Hh = 4;
// SS2 = SCALE^0.5 * sqrt(log2(e)) so that S' = S * log2(e); exp2(S') = e^S
static constexpr float SS2 = 0.4246609001440095f;

__device__ __forceinline__ void lds16(const bf16* src, bf16* dst) {
  __builtin_amdgcn_global_load_lds(
      (const __attribute__((address_space(1))) void*)src,
      (__attribute__((address_space(3))) void*)dst, 16, 0, 0);
}

__device__ __forceinline__ f32x16 zero16() {
  f32x16 t;
#pragma unroll
  for (int i = 0; i < 16; ++i) t[i] = 0.f;
  return t;
}

// ---------------- prep: weight transposes/casts + fold scaffolding + x->bf16 (R12) ----------------
__global__ __launch_bounds__(256) void prep_k(
    const float* Wqk, const float* Wv, const float* Wout, const float* bout,
    const float* Wf1, const float* Wf2, const float* x0, const float* x1,
    bf16* wqkv_t, bf16* wout_b, bf16* wfold_t, bf16* wf1b_t, bf16* wf2_t,
    bf16* xb0, bf16* xb1) {
  int id = blockIdx.x * 256 + threadIdx.x;
  if (id < 65536) { int k = id >> 8, n = id & 255; wqkv_t[n*256 + k] = (bf16)Wqk[id]; return; }
  id -= 65536;
  if (id < 65536) { int k = id >> 8, n = id & 255; wqkv_t[(256 + n)*256 + k] = (bf16)Wv[id]; return; }
  id -= 65536;
  if (id < 98304) {
    if (id < 65536) { wout_b[id] = (bf16)Wout[id]; }
    else { int id3 = id - 65536; int r = id3 >> 8, k = id3 & 255;
           wout_b[(256 + r)*256 + k] = (r == 0) ? (bf16)bout[k] : (bf16)0.f; }
    return; }
  id -= 98304;
  if (id < 131072) { int o = id & 511, k = id >> 9; wfold_t[o*512 + k] = (bf16)Wf1[k*512 + o]; return; }
  id -= 131072;
  if (id < 131072) { int o = id & 511, k = id >> 9; wf1b_t[o*256 + k] = (bf16)Wf1[(256 + k)*512 + o]; return; }
  id -= 131072;
  if (id < 131072) { int k = id >> 8, n = id & 255; wf2_t[n*512 + k] = (bf16)Wf2[id]; return; }
  id -= 131072;
  if (id < 1048576) {
    const float* xs = (id < 524288) ? x0 : x1;
    bf16* xd = (id < 524288) ? xb0 : xb1;
    int j = (id < 524288) ? id : id - 524288;
    f32x4 v = *reinterpret_cast<const f32x4*>(&xs[(size_t)j * 4]);
    bf16x4 o; o[0] = (bf16)v[0]; o[1] = (bf16)v[1]; o[2] = (bf16)v[2]; o[3] = (bf16)v[3];
    *reinterpret_cast<bf16x4*>(&xd[(size_t)j * 4]) = o;
  }
}

// ---------------- merged QKV projection + weight-fold GEMM (R12, unchanged) ----------------
__global__ __launch_bounds__(256, 2) void qkvfold_k(
    const bf16* xb0, const bf16* xb1, const bf16* wqkv_t,
    const float* bqk, const float* bv,
    bf16* qks0, bf16* qks1, bf16* vT0, bf16* vT1,
    const bf16* wout_b, const bf16* wf1b_t, const float* bf1,
    bf16* wfold_t, float* bfold) {
  const int fid = blockIdx.x;
  const bool fold = fid >= 512;
  int bx, by, bz;
  if (!fold) {
    bx = ((fid & 7) << 3) + ((fid >> 3) & 7);
    by = (fid >> 6) & 3;
    bz = fid >> 8;
  } else {
    int id = fid - 512;
    bx = id % 3; by = id / 3; bz = 0;
  }

  const bf16* Aa = fold ? wout_b : (bz ? xb1 : xb0);
  const bf16* Wt = fold ? wf1b_t : wqkv_t;

  const int tid = threadIdx.x;
  const int lane = tid & 63;
  const int w = tid >> 6;
  const int wr = w >> 1, wc = w & 1;
  const int m0r = bx * 128;
  const int n0 = by * 128;
  const int r15 = lane & 15, g = lane >> 4, rb = r15 & 7;
  const int l3 = lane >> 3, l7 = lane & 7;
  const int swzc = (l7 ^ l3) * 8;

  __shared__ bf16 At[2][8192];
  __shared__ bf16 Bt[2][8192];

  const bf16* aA = Aa + (size_t)(m0r + w*32 + l3) * 256 + swzc;
  const bf16* bB = Wt + (size_t)(n0 + w*32 + l3) * 256 + swzc;
  const int adst = (w*32) * 64;

  auto stage = [&](int buf, int kc) {
#pragma unroll
    for (int i = 0; i < 4; i++)
      lds16(aA + kc*64 + (size_t)i * 8 * 256, &At[buf][adst + i*512]);
#pragma unroll
    for (int i = 0; i < 4; i++)
      lds16(bB + kc*64 + (size_t)i * 8 * 256, &Bt[buf][adst + i*512]);
  };

  f32x4 acc[4][4];
#pragma unroll
  for (int i = 0; i < 4; i++)
#pragma unroll
    for (int j = 0; j < 4; j++) acc[i][j] = f32x4{0.f, 0.f, 0.f, 0.f};

  const int rx0 = ((0*4 + g) ^ rb) << 4;
  const int rx1 = ((1*4 + g) ^ rb) << 4;

  auto compute = [&](int cur) {
    const char* Ap = (const char*)&At[cur][0];
    const char* Bp = (const char*)&Bt[cur][0];
    __builtin_amdgcn_s_setprio(1);
#pragma unroll
    for (int ks = 0; ks < 2; ++ks) {
      const int rx = ks ? rx1 : rx0;
      bf16x8 af[4], bfr[4];
#pragma unroll
      for (int mf = 0; mf < 4; ++mf)
        af[mf] = *reinterpret_cast<const bf16x8*>(Ap + (wr*64 + mf*16 + r15) * 128 + rx);
#pragma unroll
      for (int nf = 0; nf < 4; ++nf)
        bfr[nf] = *reinterpret_cast<const bf16x8*>(Bp + (wc*64 + nf*16 + r15) * 128 + rx);
#pragma unroll
      for (int mf = 0; mf < 4; ++mf)
#pragma unroll
        for (int nf = 0; nf < 4; ++nf)
          acc[mf][nf] = MFMA(af[mf], bfr[nf], acc[mf][nf]);
    }
    __builtin_amdgcn_s_setprio(0);
  };

  stage(0, 0);
  int cur = 0;
  for (int kc = 0; kc < 3; ++kc) {
    stage(cur ^ 1, kc + 1);
    asm volatile("s_waitcnt vmcnt(8)" ::: "memory");
    __builtin_amdgcn_sched_barrier(0);
    __builtin_amdgcn_s_barrier();
    __builtin_amdgcn_sched_barrier(0);
    compute(cur);
    asm volatile("s_waitcnt lgkmcnt(0)" ::: "memory");
    __builtin_amdgcn_sched_barrier(0);
    __builtin_amdgcn_s_barrier();
    __builtin_amdgcn_sched_barrier(0);
    cur ^= 1;
  }
  asm volatile("s_waitcnt vmcnt(0)" ::: "memory");
  __builtin_amdgcn_sched_barrier(0);
  __builtin_amdgcn_s_barrier();
  __builtin_amdgcn_sched_barrier(0);
  compute(cur);

  if (!fold) {
    bf16* qks = bz ? qks1 : qks0;
    bf16* vT  = bz ? vT1  : vT0;
#pragma unroll
    for (int mf = 0; mf < 4; ++mf)
#pragma unroll
      for (int nf = 0; nf < 4; ++nf) {
        f32x4 c = acc[mf][nf];
        int cg = n0 + wc*64 + nf*16 + r15;
#pragma unroll
        for (int r = 0; r < 4; ++r) {
          int rg = m0r + wr*64 + mf*16 + g*4 + r;
          int b = rg >> 11, n = rg & 2047;
          if (cg < 256) {
            float val = (c[r] + bqk[cg]) * SS2;
            int h = cg >> 6, dh = cg & 63;
            qks[(((size_t)(b*Hh + h)) * Nn + n) * 64 + dh] = (bf16)val;
          } else {
            int c2 = cg - 256;
            float val = c[r] + bv[c2];
            int h = c2 >> 6, dh = c2 & 63;
            vT[(((size_t)(b*Hh + h)) * 64 + dh) * Nn + n] = (bf16)val;
          }
        }
      }
  } else {
#pragma unroll
    for (int mf = 0; mf < 4; ++mf)
#pragma unroll
      for (int nf = 0; nf < 4; ++nf) {
        f32x4 c = acc[mf][nf];
        int cg = n0 + wc*64 + nf*16 + r15;
#pragma unroll
        for (int r = 0; r < 4; ++r) {
          int rg = m0r + wr*64 + mf*16 + g*4 + r;
          if (rg < 256) wfold_t[(size_t)cg * 512 + 256 + rg] = (bf16)c[r];
          else if (rg == 256) bfold[cg] = c[r] + bf1[cg];
        }
      }
  }
}

// ---------------- FFN-1 row-complete GEMM + fused LayerNorm + GELU ----------------
// 64 rows x 512 cols per block (512 thr / 8 waves; wave w = all rows x cols
// w*64..+63). Full rows in-block -> LN stats are a plain in-block reduction;
// LN+GELU applied once in the epilogue from live accs; pre-LN h never written.
__global__ __launch_bounds__(512, 2) void gemm3f_k(
    const bf16* Aa0, const bf16* Aa1, const bf16* Ac0, const bf16* Ac1,
    const bf16* Wt, const float* bias,
    const float* lng, const float* lnb,
    bf16* ob0, bf16* ob1) {
  const int id = blockIdx.x;          // 256 blocks = 1 per CU
  const int bz = id >> 7, bx = id & 127;
  const bf16* Aa = bz ? Aa1 : Aa0;    // xb (K 0..255)
  const bf16* Ac = bz ? Ac1 : Ac0;    // m  (K 256..511)
  bf16* ob = bz ? ob1 : ob0;

  const int tid = threadIdx.x;
  const int lane = tid & 63;
  const int w = tid >> 6;             // 0..7
  const int m0r = bx * 64;
  const int r15 = lane & 15, g = lane >> 4, rb = r15 & 7;
  const int l3 = lane >> 3, l7 = lane & 7;
  const int swzc = (l7 ^ l3) * 8;

  __shared__ bf16 At[2][4096];        // [buf][64 rows x 64 K]
  __shared__ bf16 Bt[2][32768];       // [buf][512 cols x 64 K]

  const bf16* aA = Aa + (size_t)(m0r + w*8 + l3) * 256 + swzc;
  const bf16* aC = Ac + (size_t)(m0r + w*8 + l3) * 256 + swzc;
  const bf16* bB = Wt + (size_t)(w*64 + l3) * 512 + swzc;
  const int adst = (w*8) * 64;
  const int bdst = (w*64) * 64;

  auto stage = [&](int buf, int kc) {
    const bf16* ab = (kc < 4) ? aA : aC;
    const int kcol = (kc < 4) ? kc*64 : (kc - 4)*64;
    lds16(ab + kcol, &At[buf][adst]);                       // 1 issue: 8 rows
#pragma unroll
    for (int i = 0; i < 8; i++)                              // 8 issues: 64 cols
      lds16(bB + kc*64 + (size_t)i * 8 * 512, &Bt[buf][bdst + i*512]);
  };

  f32x4 acc[4][4];
#pragma unroll
  for (int i = 0; i < 4; i++)
#pragma unroll
    for (int j = 0; j < 4; j++) acc[i][j] = f32x4{0.f, 0.f, 0.f, 0.f};

  const int rx0 = ((0*4 + g) ^ rb) << 4;
  const int rx1 = ((1*4 + g) ^ rb) << 4;

  auto compute = [&](int cur) {
    const char* Ap = (const char*)&At[cur][0];
    const char* Bp = (const char*)&Bt[cur][0];
    __builtin_amdgcn_s_setprio(1);
#pragma unroll
    for (int ks = 0; ks < 2; ++ks) {
      const int rx = ks ? rx1 : rx0;
      bf16x8 af[4], bfr[4];
#pragma unroll
      for (int mf = 0; mf < 4; ++mf)
        af[mf] = *reinterpret_cast<const bf16x8*>(Ap + (mf*16 + r15) * 128 + rx);
#pragma unroll
      for (int nf = 0; nf < 4; ++nf)
        bfr[nf] = *reinterpret_cast<const bf16x8*>(Bp + (w*64 + nf*16 + r15) * 128 + rx);
#pragma unroll
      for (int mf = 0; mf < 4; ++mf)
#pragma unroll
        for (int nf = 0; nf < 4; ++nf)
          acc[mf][nf] = MFMA(af[mf], bfr[nf], acc[mf][nf]);
    }
    __builtin_amdgcn_s_setprio(0);
  };

  stage(0, 0);
  int cur = 0;
  for (int kc = 0; kc < 7; ++kc) {
    stage(cur ^ 1, kc + 1);
    asm volatile("s_waitcnt vmcnt(9)" ::: "memory");   // 9 issues/wave/stage
    __builtin_amdgcn_sched_barrier(0);
    __builtin_amdgcn_s_barrier();
    __builtin_amdgcn_sched_barrier(0);
    compute(cur);
    asm volatile("s_waitcnt lgkmcnt(0)" ::: "memory");
    __builtin_amdgcn_sched_barrier(0);
    __builtin_amdgcn_s_barrier();
    __builtin_amdgcn_sched_barrier(0);
    cur ^= 1;
  }
  asm volatile("s_waitcnt vmcnt(0)" ::: "memory");
  __builtin_amdgcn_sched_barrier(0);
  __builtin_amdgcn_s_barrier();
  __builtin_amdgcn_sched_barrier(0);
  compute(cur);

  // ---- epilogue: in-block LN stats over full 512-wide rows ----
  float bch[4];
#pragma unroll
  for (int nf = 0; nf < 4; ++nf) bch[nf] = bias[w*64 + nf*16 + r15];

  float s_[4][4], s2_[4][4];
#pragma unroll
  for (int mf = 0; mf < 4; ++mf)
#pragma unroll
    for (int r = 0; r < 4; ++r) {
      float s = 0.f, s2 = 0.f;
#pragma unroll
      for (int nf = 0; nf < 4; ++nf) {
        float v = acc[mf][nf][r] + bch[nf];
        s += v; s2 += v * v;
      }
      s_[mf][r] = s; s2_[mf][r] = s2;
    }
#pragma unroll
  for (int mf = 0; mf < 4; ++mf)
#pragma unroll
    for (int r = 0; r < 4; ++r) {
#pragma unroll
      for (int m = 1; m < 16; m <<= 1) {
        s_[mf][r]  += __shfl_xor(s_[mf][r],  m);
        s2_[mf][r] += __shfl_xor(s2_[mf][r], m);
      }
    }
  __syncthreads();                       // all LDS (At/Bt) reads done
  float* sred  = (float*)&At[0][0];      // [8 waves][64 rows][2] = 4 KB
  float* rstat = sred + 1024;            // [64 rows][2]
  if (r15 == 0) {
#pragma unroll
    for (int mf = 0; mf < 4; ++mf)
#pragma unroll
      for (int r = 0; r < 4; ++r) {
        int row = mf*16 + g*4 + r;
        sred[(w*64 + row)*2    ] = s_[mf][r];
        sred[(w*64 + row)*2 + 1] = s2_[mf][r];
      }
  }
  __syncthreads();
  if (tid < 64) {
    float S = 0.f, S2 = 0.f;
#pragma unroll
    for (int wv = 0; wv < 8; ++wv) {
      S  += sred[(wv*64 + tid)*2];
      S2 += sred[(wv*64 + tid)*2 + 1];
    }
    float mu = S * (1.f/512.f);
    float var = S2 * (1.f/512.f) - mu*mu;
    rstat[tid*2]     = mu;
    rstat[tid*2 + 1] = rsqrtf(var + 1e-5f);
  }
  __syncthreads();
  // ---- apply LN + GELU from live accs, write hg (only write of this tensor) ----
  float gch[4], bth[4];
#pragma unroll
  for (int nf = 0; nf < 4; ++nf) {
    int col = w*64 + nf*16 + r15;
    gch[nf] = lng[col]; bth[nf] = lnb[col];
  }
#pragma unroll
  for (int mf = 0; mf < 4; ++mf)
#pragma unroll
    for (int r = 0; r < 4; ++r) {
      int rowl = mf*16 + g*4 + r;
      float mu  = rstat[rowl*2];
      float rsv = rstat[rowl*2 + 1];
#pragma unroll
      for (int nf = 0; nf < 4; ++nf) {
        int col = w*64 + nf*16 + r15;
        float val = acc[mf][nf][r] + bch[nf];
        float xn = (val - mu) * rsv * gch[nf] + bth[nf];
        float ge = 0.5f * xn * (1.f + erff(xn * 0.70710678118f));
        ob[(size_t)(m0r + rowl) * 512 + col] = (bf16)ge;
      }
    }
}

// ---------------- pipelined MFMA GEMM (MODE 4 only): FFN-2 + residual ----------------
template<int MODE, int BN, int MINW, int REMAP>
__global__ __launch_bounds__(256, MINW) void gemm_k(
    const bf16* Aa0, const bf16* Aa1, const bf16* Ac0, const bf16* Ac1,
    const bf16* Wt, const float* bias,
    bf16* ob0, bf16* ob1, float* of0, float* of1) {
  constexpr int KD  = 512;
  constexpr int LDA = (MODE == 4) ? 512 : 256;
  constexpr int NKC = KD / 64;
  constexpr int NF  = BN / 32;

  int bx = blockIdx.x, by = blockIdx.y, bz = blockIdx.z;
  if constexpr (REMAP == 1) {
    int id = blockIdx.x + 64 * (blockIdx.y + 4 * blockIdx.z);
    bx = ((id & 7) << 3) + ((id >> 3) & 7);
    by = (id >> 6) & 3;
    bz = id >> 8;
  }

  const bf16* Aa = bz ? Aa1 : Aa0;
  const bf16* Ac = bz ? Ac1 : Ac0;
  bf16*  ob = bz ? ob1 : ob0;
  float* of = bz ? of1 : of0;
  (void)ob;

  const int tid = threadIdx.x;
  const int lane = tid & 63;
  const int w = tid >> 6;
  const int wr = w >> 1, wc = w & 1;
  const int m0r = bx * 128;
  const int n0 = by * BN;
  const int r15 = lane & 15, g = lane >> 4, rb = r15 & 7;
  const int l3 = lane >> 3, l7 = lane & 7;
  const int swzc = (l7 ^ l3) * 8;

  __shared__ bf16 At[2][8192];
  __shared__ bf16 Bt[2][BN * 64];

  const bf16* aA = Aa + (size_t)(m0r + w*32 + l3) * LDA + swzc;
  const bf16* bB = Wt + (size_t)(n0 + w*(BN/4) + l3) * KD + swzc;
  const int adst = (w*32) * 64;
  const int bdst = (w*(BN/4)) * 64;

  auto stage = [&](int buf, int kc) {
#pragma unroll
    for (int i = 0; i < 4; i++)
      lds16(aA + kc*64 + (size_t)i * 8 * LDA, &At[buf][adst + i*512]);
#pragma unroll
    for (int i = 0; i < NF; i++)
      lds16(bB + kc*64 + (size_t)i * 8 * KD, &Bt[buf][bdst + i*512]);
  };

  f32x4 acc[4][NF];
#pragma unroll
  for (int i = 0; i < 4; i++)
#pragma unroll
    for (int j = 0; j < NF; j++) acc[i][j] = f32x4{0.f, 0.f, 0.f, 0.f};

  const int rx0 = ((0*4 + g) ^ rb) << 4;
  const int rx1 = ((1*4 + g) ^ rb) << 4;

  auto compute = [&](int cur) {
    const char* Ap = (const char*)&At[cur][0];
    const char* Bp = (const char*)&Bt[cur][0];
    __builtin_amdgcn_s_setprio(1);
#pragma unroll
    for (int ks = 0; ks < 2; ++ks) {
      const int rx = ks ? rx1 : rx0;
      bf16x8 af[4], bfr[NF];
#pragma unroll
      for (int mf = 0; mf < 4; ++mf)
        af[mf] = *reinterpret_cast<const bf16x8*>(Ap + (wr*64 + mf*16 + r15) * 128 + rx);
#pragma unroll
      for (int nf = 0; nf < NF; ++nf)
        bfr[nf] = *reinterpret_cast<const bf16x8*>(Bp + (wc*(BN/2) + nf*16 + r15) * 128 + rx);
#pragma unroll
      for (int mf = 0; mf < 4; ++mf)
#pragma unroll
        for (int nf = 0; nf < NF; ++nf)
          acc[mf][nf] = MFMA(af[mf], bfr[nf], acc[mf][nf]);
    }
    __builtin_amdgcn_s_setprio(0);
  };

  stage(0, 0);
  int cur = 0;
  for (int kc = 0; kc < NKC - 1; ++kc) {
    stage(cur ^ 1, kc + 1);
    if constexpr (NF == 4) asm volatile("s_waitcnt vmcnt(8)" ::: "memory");
    else                   asm volatile("s_waitcnt vmcnt(6)" ::: "memory");
    __builtin_amdgcn_sched_barrier(0);
    __builtin_amdgcn_s_barrier();
    __builtin_amdgcn_sched_barrier(0);
    compute(cur);
    asm volatile("s_waitcnt lgkmcnt(0)" ::: "memory");
    __builtin_amdgcn_sched_barrier(0);
    __builtin_amdgcn_s_barrier();
    __builtin_amdgcn_sched_barrier(0);
    cur ^= 1;
  }
  asm volatile("s_waitcnt vmcnt(0)" ::: "memory");
  __builtin_amdgcn_sched_barrier(0);
  __builtin_amdgcn_s_barrier();
  __builtin_amdgcn_sched_barrier(0);
  compute(cur);

#pragma unroll
  for (int mf = 0; mf < 4; ++mf)
#pragma unroll
    for (int nf = 0; nf < NF; ++nf) {
      f32x4 c = acc[mf][nf];
      int cg = n0 + wc*(BN/2) + nf*16 + r15;
#pragma unroll
      for (int r = 0; r < 4; ++r) {
        int rg = m0r + wr*64 + mf*16 + g*4 + r;
        of[(size_t)rg * 256 + cg] = c[r] + bias[cg] + (float)Ac[(size_t)rg * 256 + cg];
      }
    }
}

// ---------------- fused dual-direction attention: j-SPLIT wave pairs (R14, unchanged) ----------------
__global__ __launch_bounds__(512, 4) void attn_k(
    const bf16* qks0, const bf16* qks1, const bf16* vT0, const bf16* vT1,
    bf16* m0o, bf16* m1o) {
  const int B = blockIdx.x + 16 * (blockIdx.y + 16 * blockIdx.z);
  const int xcd = B & 7, kk = B >> 3;
  const int group = 4 * xcd + (kk >> 4);
  const int it = kk & 15;
  const int bh = group & 15, dir = group >> 4;

  const bf16* Q  = (dir ? qks1 : qks0) + (size_t)bh * (Nn * 64);
  const bf16* Kp = (dir ? qks0 : qks1) + (size_t)bh * (Nn * 64);
  const bf16* Vp = (dir ? vT0  : vT1 ) + (size_t)bh * (64 * Nn);
  bf16* out = dir ? m1o : m0o;
  const int b = bh >> 2, h = bh & 3;

  const int tid = threadIdx.x, lane = tid & 63, w = tid >> 6;
  const int ig = w >> 1, hj = w & 1;
  const int l31 = lane & 31, hi = lane >> 5, xr = l31 & 7;
  const int iw = it * 128 + ig * 32;

  __shared__ char smem[65536];
  bf16* KV = (bf16*)smem;
  const int kbase = hj * 8192;
  const int vbase = 16384 + hj * 8192;

  bf16x8 qf[4];
#pragma unroll
  for (int kt = 0; kt < 4; ++kt)
    qf[kt] = *reinterpret_cast<const bf16x8*>(
        &Q[(size_t)(iw + l31) * 64 + kt*16 + hi*8]);

  f32x16 acc[2]; acc[0] = zero16(); acc[1] = zero16();
  float rsum = 0.f;

  const int l3 = lane >> 3, l7 = lane & 7;
  const int swz = ((l7 ^ l3) * 8);
  const bf16* ks0 = Kp + (size_t)(ig*16 +     l3) * 64 + swz;
  const bf16* ks1 = Kp + (size_t)(ig*16 + 8 + l3) * 64 + swz;
  const bf16* vs0 = Vp + (size_t)(ig*16 +     l3) * 2048 + swz;
  const bf16* vs1 = Vp + (size_t)(ig*16 + 8 + l3) * 2048 + swz;
  const int kd0 = (ig*16    ) * 64;
  const int kd1 = (ig*16 + 8) * 64;

  auto stage = [&](int buf, int j0) {
    lds16(ks0 + (size_t)j0 * 64, KV + kbase + buf*4096 + kd0);
    lds16(ks1 + (size_t)j0 * 64, KV + kbase + buf*4096 + kd1);
    lds16(vs0 + j0,              KV + vbase + buf*4096 + kd0);
    lds16(vs1 + j0,              KV + vbase + buf*4096 + kd1);
  };

  int kby[2][4], vby[2][4];
#pragma unroll
  for (int jm = 0; jm < 2; ++jm)
#pragma unroll
    for (int kt = 0; kt < 4; ++kt)
      kby[jm][kt] = (jm*32 + l31) * 128 + (((2*kt + hi) ^ xr) << 4);
#pragma unroll
  for (int nt = 0; nt < 2; ++nt)
#pragma unroll
    for (int gg = 0; gg < 4; ++gg)
      vby[nt][gg] = (nt*32 + l31) * 128 + (((2*gg + hi) ^ xr) << 4);

  auto compute_tile = [&](int cur) {
    const char* Kb = (const char*)(KV + kbase + cur*4096);
    const char* Vb = (const char*)(KV + vbase + cur*4096);
    f32x16 st[2];
    __builtin_amdgcn_s_setprio(1);
#pragma unroll
    for (int jm = 0; jm < 2; ++jm) {
      f32x16 t = zero16();
#pragma unroll
      for (int kt = 0; kt < 4; ++kt) {
        bf16x8 kf = *reinterpret_cast<const bf16x8*>(Kb + kby[jm][kt]);
        t = MFMA32(kf, qf[kt], t);
      }
      st[jm] = t;
    }
    __builtin_amdgcn_s_setprio(0);
    bf16x8 pa[4];
#pragma unroll
    for (int jm = 0; jm < 2; ++jm) {
      unsigned dw[8];
#pragma unroll
      for (int s = 0; s < 8; ++s) {
        float e0 = __builtin_amdgcn_exp2f(st[jm][2*s]);
        float e1 = __builtin_amdgcn_exp2f(st[jm][2*s + 1]);
        rsum += e0 + e1;
        asm("v_cvt_pk_bf16_f32 %0, %1, %2" : "=v"(dw[s]) : "v"(e0), "v"(e1));
      }
#pragma unroll
      for (int kt2 = 0; kt2 < 2; ++kt2) {
        unsigned a0 = dw[4*kt2 + 0], b0 = dw[4*kt2 + 2];
        unsigned a1 = dw[4*kt2 + 1], b1 = dw[4*kt2 + 3];
        asm volatile("v_permlane32_swap_b32 %0, %1" : "+v"(a0), "+v"(b0));
        asm volatile("v_permlane32_swap_b32 %0, %1" : "+v"(a1), "+v"(b1));
        u32x4 uu; uu[0] = a0; uu[1] = a1; uu[2] = b0; uu[3] = b1;
        pa[jm*2 + kt2] = __builtin_bit_cast(bf16x8, uu);
      }
    }
    __builtin_amdgcn_s_setprio(1);
#pragma unroll
    for (int gg = 0; gg < 4; ++gg) {
#pragma unroll
      for (int nt = 0; nt < 2; ++nt) {
        bf16x8 vf = *reinterpret_cast<const bf16x8*>(Vb + vby[nt][gg]);
        acc[nt] = MFMA32(pa[gg], vf, acc[nt]);
      }
    }
    __builtin_amdgcn_s_setprio(0);
  };

  const int jt0 = hj << 4;
  stage(0, jt0 << 6);
  int cur = 0;
  for (int t = 0; t < 15; ++t) {
    stage(cur ^ 1, (jt0 + t + 1) << 6);
    asm volatile("s_waitcnt vmcnt(4)" ::: "memory");
    __builtin_amdgcn_sched_barrier(0);
    __builtin_amdgcn_s_barrier();
    __builtin_amdgcn_sched_barrier(0);
    compute_tile(cur);
    asm volatile("s_waitcnt lgkmcnt(0)" ::: "memory");
    __builtin_amdgcn_sched_barrier(0);
    __builtin_amdgcn_s_barrier();
    __builtin_amdgcn_sched_barrier(0);
    cur ^= 1;
  }
  asm volatile("s_waitcnt vmcnt(0)" ::: "memory");
  __builtin_amdgcn_sched_barrier(0);
  __builtin_amdgcn_s_barrier();
  __builtin_amdgcn_sched_barrier(0);
  compute_tile(cur);

  rsum += __shfl_xor(rsum, 32);
  __syncthreads();
  float* Ex = (float*)smem;
  if (hj == 1) {
#pragma unroll
    for (int nt = 0; nt < 2; ++nt)
#pragma unroll
      for (int r = 0; r < 16; ++r)
        Ex[(ig*33 + nt*16 + r) * 64 + lane] = acc[nt][r];
    Ex[(ig*33 + 32) * 64 + lane] = rsum;
  }
  __syncthreads();
  if (hj == 0) {
    float tot = rsum + Ex[(ig*33 + 32) * 64 + lane];
    float* Rt2 = (float*)(smem + 49152);
    if (lane < 32) Rt2[ig*32 + l31] = tot;
    f32x4 rv[4];
#pragma unroll
    for (int q = 0; q < 4; ++q)
      rv[q] = *reinterpret_cast<const f32x4*>(&Rt2[ig*32 + 8*q + 4*hi]);
#pragma unroll
    for (int r = 0; r < 16; ++r) {
      float inv = 1.0f / rv[r >> 2][r & 3];
      int row = iw + (r & 3) + 8*(r >> 2) + 4*hi;
#pragma unroll
      for (int nt = 0; nt < 2; ++nt) {
        float o = acc[nt][r] + Ex[(ig*33 + nt*16 + r) * 64 + lane];
        int col = h*64 + nt*32 + l31;
        out[((size_t)b * Nn + row) * 256 + col] = (bf16)(o * inv);
      }
    }
  }
}

extern "C" void kernel_launch(void* const* d_in, const int* in_sizes, int n_in,
                              void* d_out, int out_size, void* d_ws, size_t ws_size,
                              hipStream_t stream) {
  (void)in_sizes; (void)n_in; (void)out_size; (void)ws_size;
  const float* x0   = (const float*)d_in[0];
  const float* x1   = (const float*)d_in[1];
  const float* Wqk  = (const float*)d_in[2];
  const float* bqk  = (const float*)d_in[3];
  const float* Wv   = (const float*)d_in[4];
  const float* bv   = (const float*)d_in[5];
  const float* Wout = (const float*)d_in[6];
  const float* bout = (const float*)d_in[7];
  const float* Wf1  = (const float*)d_in[8];
  const float* bf1  = (const float*)d_in[9];
  const float* ln_g = (const float*)d_in[10];
  const float* ln_b = (const float*)d_in[11];
  const float* Wf2  = (const float*)d_in[12];
  const float* bf2  = (const float*)d_in[13];
  float* y = (float*)d_out;

  bf16* p = (bf16*)d_ws;
  bf16* wqkv_t = p; p += 131072;
  bf16* wout_b = p; p += 98304;
  bf16* wfold_t = p; p += 262144;
  bf16* wf1b_t = p; p += 131072;
  bf16* wf2_t  = p; p += 131072;
  float* bfold = (float*)p; p += 1024;     // 512 f32
  bf16* xb0  = p; p += 2097152;
  bf16* xb1  = p; p += 2097152;
  bf16* qks0 = p; p += 2097152;
  bf16* qks1 = p; p += 2097152;
  bf16* vT0  = p; p += 2097152;
  bf16* vT1  = p; p += 2097152;
  bf16* m0   = p; p += 2097152;
  bf16* m1   = p; p += 2097152;
  bf16* hg0  = p; p += 4194304;
  bf16* hg1  = p; p += 4194304;

  dim3 blk(256);
  prep_k<<<6528, blk, 0, stream>>>(Wqk, Wv, Wout, bout, Wf1, Wf2, x0, x1,
                                   wqkv_t, wout_b, wfold_t, wf1b_t, wf2_t, xb0, xb1);
  qkvfold_k<<<dim3(524), blk, 0, stream>>>(
      xb0, xb1, wqkv_t, bqk, bv, qks0, qks1, vT0, vT1,
      wout_b, wf1b_t, bf1, wfold_t, bfold);
  attn_k<<<dim3(16, 16, 2), dim3(512), 0, stream>>>(qks0, qks1, vT0, vT1, m0, m1);
  // FFN-1 + LN + GELU fused (row-complete 64x512 tiles; ln kernel deleted)
  gemm3f_k<<<dim3(256), dim3(512), 0, stream>>>(
      xb0, xb1, m0, m1, wfold_t, bfold, ln_g, ln_b, hg0, hg1);
  gemm_k<4,64,3,1><<<dim3(64, 4, 2), blk, 0, stream>>>(
      hg0, hg1, xb0, xb1, wf2_t, bf2,
      nullptr, nullptr, y, y + 2097152);
}

// Round 16
// 112.859 us; speedup vs baseline: 1.1009x; 1.1009x over previous
//
#include <hip/hip_runtime.h>
#include <hip/hip_bf16.h>
#include <math.h>

typedef __bf16 bf16;
typedef __attribute__((ext_vector_type(8))) __bf16 bf16x8;
typedef __attribute__((ext_vector_type(4))) __bf16 bf16x4;
typedef __attribute__((ext_vector_type(2))) __bf16 bf16x2;
typedef __attribute__((ext_vector_type(4))) float f32x4;
typedef __attribute__((ext_vector_type(16))) float f32x16;
typedef __attribute__((ext_vector_type(4))) unsigned u32x4;

#define MFMA(a,b,c)   __builtin_amdgcn_mfma_f32_16x16x32_bf16(a,b,c,0,0,0)
#define MFMA32(a,b,c) __builtin_amdgcn_mfma_f32_32x32x16_bf16(a,b,c,0,0,0)

static constexpr int Bb = 4, Nn = 2048, Hh = 4;
// SS2 = SCALE^0.5 * sqrt(log2(e)) so that S' = S * log2(e); exp2(S') = e^S
static constexpr float SS2 = 0.4246609001440095f;

__device__ __forceinline__ void lds16(const bf16* src, bf16* dst) {
  __builtin_amdgcn_global_load_lds(
      (const __attribute__((address_space(1))) void*)src,
      (__attribute__((address_space(3))) void*)dst, 16, 0, 0);
}

__device__ __forceinline__ f32x16 zero16() {
  f32x16 t;
#pragma unroll
  for (int i = 0; i < 16; ++i) t[i] = 0.f;
  return t;
}

// ---------------- prep: weight transposes/casts + fold scaffolding + x->bf16 (R12) ----------------
__global__ __launch_bounds__(256) void prep_k(
    const float* Wqk, const float* Wv, const float* Wout, const float* bout,
    const float* Wf1, const float* Wf2, const float* x0, const float* x1,
    bf16* wqkv_t, bf16* wout_b, bf16* wfold_t, bf16* wf1b_t, bf16* wf2_t,
    bf16* xb0, bf16* xb1) {
  int id = blockIdx.x * 256 + threadIdx.x;
  if (id < 65536) { int k = id >> 8, n = id & 255; wqkv_t[n*256 + k] = (bf16)Wqk[id]; return; }
  id -= 65536;
  if (id < 65536) { int k = id >> 8, n = id & 255; wqkv_t[(256 + n)*256 + k] = (bf16)Wv[id]; return; }
  id -= 65536;
  if (id < 98304) {
    if (id < 65536) { wout_b[id] = (bf16)Wout[id]; }
    else { int id3 = id - 65536; int r = id3 >> 8, k = id3 & 255;
           wout_b[(256 + r)*256 + k] = (r == 0) ? (bf16)bout[k] : (bf16)0.f; }
    return; }
  id -= 98304;
  if (id < 131072) { int o = id & 511, k = id >> 9; wfold_t[o*512 + k] = (bf16)Wf1[k*512 + o]; return; }
  id -= 131072;
  if (id < 131072) { int o = id & 511, k = id >> 9; wf1b_t[o*256 + k] = (bf16)Wf1[(256 + k)*512 + o]; return; }
  id -= 131072;
  if (id < 131072) { int k = id >> 8, n = id & 255; wf2_t[n*512 + k] = (bf16)Wf2[id]; return; }
  id -= 131072;
  if (id < 1048576) {
    const float* xs = (id < 524288) ? x0 : x1;
    bf16* xd = (id < 524288) ? xb0 : xb1;
    int j = (id < 524288) ? id : id - 524288;
    f32x4 v = *reinterpret_cast<const f32x4*>(&xs[(size_t)j * 4]);
    bf16x4 o; o[0] = (bf16)v[0]; o[1] = (bf16)v[1]; o[2] = (bf16)v[2]; o[3] = (bf16)v[3];
    *reinterpret_cast<bf16x4*>(&xd[(size_t)j * 4]) = o;
  }
}

// ---------------- merged QKV projection + weight-fold GEMM ----------------
// V-epilogue now transposes through a swizzled 32 KB LDS tile so the
// vT store is coalesced 16 B runs along n (was: 2 B scatter at 4 KB stride).
__global__ __launch_bounds__(256, 2) void qkvfold_k(
    const bf16* xb0, const bf16* xb1, const bf16* wqkv_t,
    const float* bqk, const float* bv,
    bf16* qks0, bf16* qks1, bf16* vT0, bf16* vT1,
    const bf16* wout_b, const bf16* wf1b_t, const float* bf1,
    bf16* wfold_t, float* bfold) {
  const int fid = blockIdx.x;
  const bool fold = fid >= 512;
  int bx, by, bz;
  if (!fold) {
    bx = ((fid & 7) << 3) + ((fid >> 3) & 7);
    by = (fid >> 6) & 3;
    bz = fid >> 8;
  } else {
    int id = fid - 512;
    bx = id % 3; by = id / 3; bz = 0;
  }

  const bf16* Aa = fold ? wout_b : (bz ? xb1 : xb0);
  const bf16* Wt = fold ? wf1b_t : wqkv_t;

  const int tid = threadIdx.x;
  const int lane = tid & 63;
  const int w = tid >> 6;
  const int wr = w >> 1, wc = w & 1;
  const int m0r = bx * 128;
  const int n0 = by * 128;
  const int r15 = lane & 15, g = lane >> 4, rb = r15 & 7;
  const int l3 = lane >> 3, l7 = lane & 7;
  const int swzc = (l7 ^ l3) * 8;

  __shared__ bf16 At[2][8192];
  __shared__ bf16 Bt[2][8192];

  const bf16* aA = Aa + (size_t)(m0r + w*32 + l3) * 256 + swzc;
  const bf16* bB = Wt + (size_t)(n0 + w*32 + l3) * 256 + swzc;
  const int adst = (w*32) * 64;

  auto stage = [&](int buf, int kc) {
#pragma unroll
    for (int i = 0; i < 4; i++)
      lds16(aA + kc*64 + (size_t)i * 8 * 256, &At[buf][adst + i*512]);
#pragma unroll
    for (int i = 0; i < 4; i++)
      lds16(bB + kc*64 + (size_t)i * 8 * 256, &Bt[buf][adst + i*512]);
  };

  f32x4 acc[4][4];
#pragma unroll
  for (int i = 0; i < 4; i++)
#pragma unroll
    for (int j = 0; j < 4; j++) acc[i][j] = f32x4{0.f, 0.f, 0.f, 0.f};

  const int rx0 = ((0*4 + g) ^ rb) << 4;
  const int rx1 = ((1*4 + g) ^ rb) << 4;

  auto compute = [&](int cur) {
    const char* Ap = (const char*)&At[cur][0];
    const char* Bp = (const char*)&Bt[cur][0];
    __builtin_amdgcn_s_setprio(1);
#pragma unroll
    for (int ks = 0; ks < 2; ++ks) {
      const int rx = ks ? rx1 : rx0;
      bf16x8 af[4], bfr[4];
#pragma unroll
      for (int mf = 0; mf < 4; ++mf)
        af[mf] = *reinterpret_cast<const bf16x8*>(Ap + (wr*64 + mf*16 + r15) * 128 + rx);
#pragma unroll
      for (int nf = 0; nf < 4; ++nf)
        bfr[nf] = *reinterpret_cast<const bf16x8*>(Bp + (wc*64 + nf*16 + r15) * 128 + rx);
#pragma unroll
      for (int mf = 0; mf < 4; ++mf)
#pragma unroll
        for (int nf = 0; nf < 4; ++nf)
          acc[mf][nf] = MFMA(af[mf], bfr[nf], acc[mf][nf]);
    }
    __builtin_amdgcn_s_setprio(0);
  };

  stage(0, 0);
  int cur = 0;
  for (int kc = 0; kc < 3; ++kc) {
    stage(cur ^ 1, kc + 1);
    asm volatile("s_waitcnt vmcnt(8)" ::: "memory");
    __builtin_amdgcn_sched_barrier(0);
    __builtin_amdgcn_s_barrier();
    __builtin_amdgcn_sched_barrier(0);
    compute(cur);
    asm volatile("s_waitcnt lgkmcnt(0)" ::: "memory");
    __builtin_amdgcn_sched_barrier(0);
    __builtin_amdgcn_s_barrier();
    __builtin_amdgcn_sched_barrier(0);
    cur ^= 1;
  }
  asm volatile("s_waitcnt vmcnt(0)" ::: "memory");
  __builtin_amdgcn_sched_barrier(0);
  __builtin_amdgcn_s_barrier();
  __builtin_amdgcn_sched_barrier(0);
  compute(cur);

  if (!fold) {
    bf16* qks = bz ? qks1 : qks0;
    bf16* vT  = bz ? vT1  : vT0;
    if (by < 2) {
      // ---- Q path (unchanged) ----
#pragma unroll
      for (int mf = 0; mf < 4; ++mf)
#pragma unroll
        for (int nf = 0; nf < 4; ++nf) {
          f32x4 c = acc[mf][nf];
          int cg = n0 + wc*64 + nf*16 + r15;
#pragma unroll
          for (int r = 0; r < 4; ++r) {
            int rg = m0r + wr*64 + mf*16 + g*4 + r;
            int b = rg >> 11, n = rg & 2047;
            float val = (c[r] + bqk[cg]) * SS2;
            int h = cg >> 6, dh = cg & 63;
            qks[(((size_t)(b*Hh + h)) * Nn + n) * 64 + dh] = (bf16)val;
          }
        }
    } else {
      // ---- V path: LDS transpose (swizzled) + coalesced store along n ----
      __syncthreads();                       // all LDS reads drained
      char* T = (char*)&At[0][0];            // 32 KB tile: [c2l 128][n 128] bf16
#pragma unroll
      for (int mf = 0; mf < 4; ++mf)
#pragma unroll
        for (int nf = 0; nf < 4; ++nf) {
          f32x4 c = acc[mf][nf];
          int cl = wc*64 + nf*16 + r15;      // local col 0..127
          float bvv = bv[(by - 2) * 128 + cl];
          int rl = wr*64 + mf*16 + g*4;      // local row base (8B-aligned *2)
          bf16x4 o;
          o[0] = (bf16)(c[0] + bvv); o[1] = (bf16)(c[1] + bvv);
          o[2] = (bf16)(c[2] + bvv); o[3] = (bf16)(c[3] + bvv);
          int boff = cl*256 + ((rl*2) ^ ((cl & 15) << 4));
          *reinterpret_cast<bf16x4*>(T + boff) = o;
        }
      __syncthreads();
      const int cl = tid >> 1, nh = tid & 1;
      const int c2 = (by - 2) * 128 + cl;
      const int h = c2 >> 6, dh = c2 & 63;
      const int b = m0r >> 11, nbase = (m0r & 2047) + nh*64;
      bf16* dst = vT + (((size_t)(b*Hh + h)) * 64 + dh) * 2048 + nbase;
#pragma unroll
      for (int i = 0; i < 8; ++i) {
        int nl = nh*64 + i*8;
        int boff = cl*256 + ((nl*2) ^ ((cl & 15) << 4));
        *reinterpret_cast<uint4*>(dst + i*8) = *reinterpret_cast<const uint4*>(T + boff);
      }
    }
  } else {
#pragma unroll
    for (int mf = 0; mf < 4; ++mf)
#pragma unroll
      for (int nf = 0; nf < 4; ++nf) {
        f32x4 c = acc[mf][nf];
        int cg = n0 + wc*64 + nf*16 + r15;
#pragma unroll
        for (int r = 0; r < 4; ++r) {
          int rg = m0r + wr*64 + mf*16 + g*4 + r;
          if (rg < 256) wfold_t[(size_t)cg * 512 + 256 + rg] = (bf16)c[r];
          else if (rg == 256) bfold[cg] = c[r] + bf1[cg];
        }
      }
  }
}

// ---------------- pipelined MFMA GEMM, 128xBN tile, BK=64, dbuf + lds16 (R14) ----------------
// MODE 3: A=xb|m (concat, K=512), out=acc+bfold -> hg bf16 [8192,512]
// MODE 4: A=hg (lda512), out=acc+bf2+xb(Ac) -> y f32 [8192,256]
template<int MODE, int BN, int MINW, int REMAP>
__global__ __launch_bounds__(256, MINW) void gemm_k(
    const bf16* Aa0, const bf16* Aa1, const bf16* Ac0, const bf16* Ac1,
    const bf16* Wt, const float* bias,
    bf16* ob0, bf16* ob1, float* of0, float* of1) {
  constexpr int KD  = 512;
  constexpr int LDA = (MODE == 4) ? 512 : 256;
  constexpr int NKC = KD / 64;
  constexpr int NF  = BN / 32;

  int bx = blockIdx.x, by = blockIdx.y, bz = blockIdx.z;
  if constexpr (REMAP == 1) {
    int id = blockIdx.x + 64 * (blockIdx.y + 4 * blockIdx.z);
    bx = ((id & 7) << 3) + ((id >> 3) & 7);
    by = (id >> 6) & 3;
    bz = id >> 8;
  }

  const bf16* Aa = bz ? Aa1 : Aa0;
  const bf16* Ac = bz ? Ac1 : Ac0;
  bf16*  ob = bz ? ob1 : ob0;
  float* of = bz ? of1 : of0;

  const int tid = threadIdx.x;
  const int lane = tid & 63;
  const int w = tid >> 6;
  const int wr = w >> 1, wc = w & 1;
  const int m0r = bx * 128;
  const int n0 = by * BN;
  const int r15 = lane & 15, g = lane >> 4, rb = r15 & 7;
  const int l3 = lane >> 3, l7 = lane & 7;
  const int swzc = (l7 ^ l3) * 8;

  __shared__ bf16 At[2][8192];
  __shared__ bf16 Bt[2][BN * 64];

  const bf16* aA = Aa + (size_t)(m0r + w*32 + l3) * LDA + swzc;
  const bf16* aC = (MODE == 3) ? (Ac + (size_t)(m0r + w*32 + l3) * 256 + swzc) : nullptr;
  const bf16* bB = Wt + (size_t)(n0 + w*(BN/4) + l3) * KD + swzc;
  const int adst = (w*32) * 64;
  const int bdst = (w*(BN/4)) * 64;

  auto stage = [&](int buf, int kc) {
    const bf16* ab; int kcol;
    if constexpr (MODE == 3) {
      if (kc < 4) { ab = aA; kcol = kc * 64; } else { ab = aC; kcol = (kc - 4) * 64; }
    } else { ab = aA; kcol = kc * 64; }
#pragma unroll
    for (int i = 0; i < 4; i++)
      lds16(ab + kcol + (size_t)i * 8 * LDA, &At[buf][adst + i*512]);
#pragma unroll
    for (int i = 0; i < NF; i++)
      lds16(bB + kc*64 + (size_t)i * 8 * KD, &Bt[buf][bdst + i*512]);
  };

  f32x4 acc[4][NF];
#pragma unroll
  for (int i = 0; i < 4; i++)
#pragma unroll
    for (int j = 0; j < NF; j++) acc[i][j] = f32x4{0.f, 0.f, 0.f, 0.f};

  const int rx0 = ((0*4 + g) ^ rb) << 4;
  const int rx1 = ((1*4 + g) ^ rb) << 4;

  auto compute = [&](int cur) {
    const char* Ap = (const char*)&At[cur][0];
    const char* Bp = (const char*)&Bt[cur][0];
    __builtin_amdgcn_s_setprio(1);
#pragma unroll
    for (int ks = 0; ks < 2; ++ks) {
      const int rx = ks ? rx1 : rx0;
      bf16x8 af[4], bfr[NF];
#pragma unroll
      for (int mf = 0; mf < 4; ++mf)
        af[mf] = *reinterpret_cast<const bf16x8*>(Ap + (wr*64 + mf*16 + r15) * 128 + rx);
#pragma unroll
      for (int nf = 0; nf < NF; ++nf)
        bfr[nf] = *reinterpret_cast<const bf16x8*>(Bp + (wc*(BN/2) + nf*16 + r15) * 128 + rx);
#pragma unroll
      for (int mf = 0; mf < 4; ++mf)
#pragma unroll
        for (int nf = 0; nf < NF; ++nf)
          acc[mf][nf] = MFMA(af[mf], bfr[nf], acc[mf][nf]);
    }
    __builtin_amdgcn_s_setprio(0);
  };

  stage(0, 0);
  int cur = 0;
  for (int kc = 0; kc < NKC - 1; ++kc) {
    stage(cur ^ 1, kc + 1);
    if constexpr (NF == 4) asm volatile("s_waitcnt vmcnt(8)" ::: "memory");
    else                   asm volatile("s_waitcnt vmcnt(6)" ::: "memory");
    __builtin_amdgcn_sched_barrier(0);
    __builtin_amdgcn_s_barrier();
    __builtin_amdgcn_sched_barrier(0);
    compute(cur);
    asm volatile("s_waitcnt lgkmcnt(0)" ::: "memory");
    __builtin_amdgcn_sched_barrier(0);
    __builtin_amdgcn_s_barrier();
    __builtin_amdgcn_sched_barrier(0);
    cur ^= 1;
  }
  asm volatile("s_waitcnt vmcnt(0)" ::: "memory");
  __builtin_amdgcn_sched_barrier(0);
  __builtin_amdgcn_s_barrier();
  __builtin_amdgcn_sched_barrier(0);
  compute(cur);

#pragma unroll
  for (int mf = 0; mf < 4; ++mf)
#pragma unroll
    for (int nf = 0; nf < NF; ++nf) {
      f32x4 c = acc[mf][nf];
      int cg = n0 + wc*(BN/2) + nf*16 + r15;
#pragma unroll
      for (int r = 0; r < 4; ++r) {
        int rg = m0r + wr*64 + mf*16 + g*4 + r;
        if constexpr (MODE == 3) {
          ob[(size_t)rg * 512 + cg] = (bf16)(c[r] + bias[cg]);
        } else {   // MODE 4
          of[(size_t)rg * 256 + cg] = c[r] + bias[cg] + (float)Ac[(size_t)rg * 256 + cg];
        }
      }
    }
}

// ---------------- fused dual-direction attention: j-SPLIT wave pairs ----------------
// R14 structure; sched_barrier(0) order-pins removed (chain-latency-bound —
// give the scheduler freedom; memory ordering still enforced by the
// "memory"-clobbered waitcnts + raw barriers).
__global__ __launch_bounds__(512, 4) void attn_k(
    const bf16* qks0, const bf16* qks1, const bf16* vT0, const bf16* vT1,
    bf16* m0o, bf16* m1o) {
  const int B = blockIdx.x + 16 * (blockIdx.y + 16 * blockIdx.z);
  const int xcd = B & 7, kk = B >> 3;
  const int group = 4 * xcd + (kk >> 4);
  const int it = kk & 15;
  const int bh = group & 15, dir = group >> 4;

  const bf16* Q  = (dir ? qks1 : qks0) + (size_t)bh * (Nn * 64);
  const bf16* Kp = (dir ? qks0 : qks1) + (size_t)bh * (Nn * 64);
  const bf16* Vp = (dir ? vT0  : vT1 ) + (size_t)bh * (64 * Nn);
  bf16* out = dir ? m1o : m0o;
  const int b = bh >> 2, h = bh & 3;

  const int tid = threadIdx.x, lane = tid & 63, w = tid >> 6;
  const int ig = w >> 1, hj = w & 1;
  const int l31 = lane & 31, hi = lane >> 5, xr = l31 & 7;
  const int iw = it * 128 + ig * 32;

  __shared__ char smem[65536];
  bf16* KV = (bf16*)smem;
  const int kbase = hj * 8192;
  const int vbase = 16384 + hj * 8192;

  bf16x8 qf[4];
#pragma unroll
  for (int kt = 0; kt < 4; ++kt)
    qf[kt] = *reinterpret_cast<const bf16x8*>(
        &Q[(size_t)(iw + l31) * 64 + kt*16 + hi*8]);

  f32x16 acc[2]; acc[0] = zero16(); acc[1] = zero16();
  float rsum = 0.f;

  const int l3 = lane >> 3, l7 = lane & 7;
  const int swz = ((l7 ^ l3) * 8);
  const bf16* ks0 = Kp + (size_t)(ig*16 +     l3) * 64 + swz;
  const bf16* ks1 = Kp + (size_t)(ig*16 + 8 + l3) * 64 + swz;
  const bf16* vs0 = Vp + (size_t)(ig*16 +     l3) * 2048 + swz;
  const bf16* vs1 = Vp + (size_t)(ig*16 + 8 + l3) * 2048 + swz;
  const int kd0 = (ig*16    ) * 64;
  const int kd1 = (ig*16 + 8) * 64;

  auto stage = [&](int buf, int j0) {
    lds16(ks0 + (size_t)j0 * 64, KV + kbase + buf*4096 + kd0);
    lds16(ks1 + (size_t)j0 * 64, KV + kbase + buf*4096 + kd1);
    lds16(vs0 + j0,              KV + vbase + buf*4096 + kd0);
    lds16(vs1 + j0,              KV + vbase + buf*4096 + kd1);
  };

  int kby[2][4], vby[2][4];
#pragma unroll
  for (int jm = 0; jm < 2; ++jm)
#pragma unroll
    for (int kt = 0; kt < 4; ++kt)
      kby[jm][kt] = (jm*32 + l31) * 128 + (((2*kt + hi) ^ xr) << 4);
#pragma unroll
  for (int nt = 0; nt < 2; ++nt)
#pragma unroll
    for (int gg = 0; gg < 4; ++gg)
      vby[nt][gg] = (nt*32 + l31) * 128 + (((2*gg + hi) ^ xr) << 4);

  auto compute_tile = [&](int cur) {
    const char* Kb = (const char*)(KV + kbase + cur*4096);
    const char* Vb = (const char*)(KV + vbase + cur*4096);
    f32x16 st[2];
    __builtin_amdgcn_s_setprio(1);
#pragma unroll
    for (int jm = 0; jm < 2; ++jm) {
      f32x16 t = zero16();
#pragma unroll
      for (int kt = 0; kt < 4; ++kt) {
        bf16x8 kf = *reinterpret_cast<const bf16x8*>(Kb + kby[jm][kt]);
        t = MFMA32(kf, qf[kt], t);
      }
      st[jm] = t;
    }
    __builtin_amdgcn_s_setprio(0);
    bf16x8 pa[4];
#pragma unroll
    for (int jm = 0; jm < 2; ++jm) {
      unsigned dw[8];
#pragma unroll
      for (int s = 0; s < 8; ++s) {
        float e0 = __builtin_amdgcn_exp2f(st[jm][2*s]);
        float e1 = __builtin_amdgcn_exp2f(st[jm][2*s + 1]);
        rsum += e0 + e1;
        asm("v_cvt_pk_bf16_f32 %0, %1, %2" : "=v"(dw[s]) : "v"(e0), "v"(e1));
      }
#pragma unroll
      for (int kt2 = 0; kt2 < 2; ++kt2) {
        unsigned a0 = dw[4*kt2 + 0], b0 = dw[4*kt2 + 2];
        unsigned a1 = dw[4*kt2 + 1], b1 = dw[4*kt2 + 3];
        asm volatile("v_permlane32_swap_b32 %0, %1" : "+v"(a0), "+v"(b0));
        asm volatile("v_permlane32_swap_b32 %0, %1" : "+v"(a1), "+v"(b1));
        u32x4 uu; uu[0] = a0; uu[1] = a1; uu[2] = b0; uu[3] = b1;
        pa[jm*2 + kt2] = __builtin_bit_cast(bf16x8, uu);
      }
    }
    __builtin_amdgcn_s_setprio(1);
#pragma unroll
    for (int gg = 0; gg < 4; ++gg) {
#pragma unroll
      for (int nt = 0; nt < 2; ++nt) {
        bf16x8 vf = *reinterpret_cast<const bf16x8*>(Vb + vby[nt][gg]);
        acc[nt] = MFMA32(pa[gg], vf, acc[nt]);
      }
    }
    __builtin_amdgcn_s_setprio(0);
  };

  const int jt0 = hj << 4;
  stage(0, jt0 << 6);
  int cur = 0;
  for (int t = 0; t < 15; ++t) {
    stage(cur ^ 1, (jt0 + t + 1) << 6);
    asm volatile("s_waitcnt vmcnt(4)" ::: "memory");
    __builtin_amdgcn_s_barrier();
    compute_tile(cur);
    asm volatile("s_waitcnt lgkmcnt(0)" ::: "memory");
    __builtin_amdgcn_s_barrier();
    cur ^= 1;
  }
  asm volatile("s_waitcnt vmcnt(0)" ::: "memory");
  __builtin_amdgcn_s_barrier();
  compute_tile(cur);

  // ---- epilogue: combine hi-halves, then hj-halves via LDS, redistribute, write ----
  rsum += __shfl_xor(rsum, 32);
  __syncthreads();
  float* Ex = (float*)smem;
  if (hj == 1) {
#pragma unroll
    for (int nt = 0; nt < 2; ++nt)
#pragma unroll
      for (int r = 0; r < 16; ++r)
        Ex[(ig*33 + nt*16 + r) * 64 + lane] = acc[nt][r];
    Ex[(ig*33 + 32) * 64 + lane] = rsum;
  }
  __syncthreads();
  if (hj == 0) {
    float tot = rsum + Ex[(ig*33 + 32) * 64 + lane];
    float* Rt2 = (float*)(smem + 49152);
    if (lane < 32) Rt2[ig*32 + l31] = tot;
    f32x4 rv[4];
#pragma unroll
    for (int q = 0; q < 4; ++q)
      rv[q] = *reinterpret_cast<const f32x4*>(&Rt2[ig*32 + 8*q + 4*hi]);
#pragma unroll
    for (int r = 0; r < 16; ++r) {
      float inv = 1.0f / rv[r >> 2][r & 3];
      int row = iw + (r & 3) + 8*(r >> 2) + 4*hi;
#pragma unroll
      for (int nt = 0; nt < 2; ++nt) {
        float o = acc[nt][r] + Ex[(ig*33 + nt*16 + r) * 64 + lane];
        int col = h*64 + nt*32 + l31;
        out[((size_t)b * Nn + row) * 256 + col] = (bf16)(o * inv);
      }
    }
  }
}

// ---------------- LayerNorm + exact GELU: one wave per 512-col row (R14) ----------------
__global__ __launch_bounds__(256) void ln_gelu_k(
    bf16* hg, const float* g, const float* bb) {
  const int row = (blockIdx.x << 2) + (threadIdx.x >> 6);
  const int lane = threadIdx.x & 63;
  bf16* hr = hg + (size_t)row * 512 + lane * 8;
  bf16x8 v = *reinterpret_cast<const bf16x8*>(hr);
  float f[8];
  float s = 0.f, sq = 0.f;
#pragma unroll
  for (int i = 0; i < 8; ++i) { f[i] = (float)v[i]; s += f[i]; sq += f[i]*f[i]; }
#pragma unroll
  for (int m = 1; m < 64; m <<= 1) { s += __shfl_xor(s, m); sq += __shfl_xor(sq, m); }
  float mu = s * (1.f / 512.f);
  float var = sq * (1.f / 512.f) - mu * mu;
  float rsv = rsqrtf(var + 1e-5f);
  f32x4 g0 = *reinterpret_cast<const f32x4*>(&g[lane*8]);
  f32x4 g1 = *reinterpret_cast<const f32x4*>(&g[lane*8 + 4]);
  f32x4 b0 = *reinterpret_cast<const f32x4*>(&bb[lane*8]);
  f32x4 b1 = *reinterpret_cast<const f32x4*>(&bb[lane*8 + 4]);
  bf16x8 o;
#pragma unroll
  for (int i = 0; i < 8; ++i) {
    float gv = (i < 4) ? g0[i] : g1[i-4];
    float bv = (i < 4) ? b0[i] : b1[i-4];
    float xn = (f[i] - mu) * rsv * gv + bv;
    float ge = 0.5f * xn * (1.f + erff(xn * 0.70710678118f));
    o[i] = (bf16)ge;
  }
  *reinterpret_cast<bf16x8*>(hr) = o;
}

extern "C" void kernel_launch(void* const* d_in, const int* in_sizes, int n_in,
                              void* d_out, int out_size, void* d_ws, size_t ws_size,
                              hipStream_t stream) {
  (void)in_sizes; (void)n_in; (void)out_size; (void)ws_size;
  const float* x0   = (const float*)d_in[0];
  const float* x1   = (const float*)d_in[1];
  const float* Wqk  = (const float*)d_in[2];
  const float* bqk  = (const float*)d_in[3];
  const float* Wv   = (const float*)d_in[4];
  const float* bv   = (const float*)d_in[5];
  const float* Wout = (const float*)d_in[6];
  const float* bout = (const float*)d_in[7];
  const float* Wf1  = (const float*)d_in[8];
  const float* bf1  = (const float*)d_in[9];
  const float* ln_g = (const float*)d_in[10];
  const float* ln_b = (const float*)d_in[11];
  const float* Wf2  = (const float*)d_in[12];
  const float* bf2  = (const float*)d_in[13];
  float* y = (float*)d_out;

  bf16* p = (bf16*)d_ws;
  bf16* wqkv_t = p; p += 131072;
  bf16* wout_b = p; p += 98304;
  bf16* wfold_t = p; p += 262144;
  bf16* wf1b_t = p; p += 131072;
  bf16* wf2_t  = p; p += 131072;
  float* bfold = (float*)p; p += 1024;     // 512 f32
  bf16* xb0  = p; p += 2097152;
  bf16* xb1  = p; p += 2097152;
  bf16* qks0 = p; p += 2097152;
  bf16* qks1 = p; p += 2097152;
  bf16* vT0  = p; p += 2097152;
  bf16* vT1  = p; p += 2097152;
  bf16* m0   = p; p += 2097152;
  bf16* m1   = p; p += 2097152;
  bf16* hg0  = p; p += 4194304;
  bf16* hg1  = p; p += 4194304;

  dim3 blk(256);
  prep_k<<<6528, blk, 0, stream>>>(Wqk, Wv, Wout, bout, Wf1, Wf2, x0, x1,
                                   wqkv_t, wout_b, wfold_t, wf1b_t, wf2_t, xb0, xb1);
  qkvfold_k<<<dim3(524), blk, 0, stream>>>(
      xb0, xb1, wqkv_t, bqk, bv, qks0, qks1, vT0, vT1,
      wout_b, wf1b_t, bf1, wfold_t, bfold);
  attn_k<<<dim3(16, 16, 2), dim3(512), 0, stream>>>(qks0, qks1, vT0, vT1, m0, m1);
  gemm_k<3,128,2,1><<<dim3(64, 4, 2), blk, 0, stream>>>(
      xb0, xb1, m0, m1, wfold_t, bfold,
      hg0, hg1, nullptr, nullptr);
  ln_gelu_k<<<dim3(4096), blk, 0, stream>>>(hg0, ln_g, ln_b);
  gemm_k<4,64,3,0><<<dim3(64, 4, 2), blk, 0, stream>>>(
      hg0, hg1, xb0, xb1, wf2_t, bf2,
      nullptr, nullptr, y, y + 2097152);
}

// Round 17
// 110.505 us; speedup vs baseline: 1.1243x; 1.0213x over previous
//
#include <hip/hip_runtime.h>
#include <hip/hip_bf16.h>
#include <math.h>

typedef __bf16 bf16;
typedef __attribute__((ext_vector_type(8))) __bf16 bf16x8;
typedef __attribute__((ext_vector_type(4))) __bf16 bf16x4;
typedef __attribute__((ext_vector_type(2))) __bf16 bf16x2;
typedef __attribute__((ext_vector_type(4))) float f32x4;
typedef __attribute__((ext_vector_type(16))) float f32x16;
typedef __attribute__((ext_vector_type(4))) unsigned u32x4;

#define MFMA(a,b,c)   __builtin_amdgcn_mfma_f32_16x16x32_bf16(a,b,c,0,0,0)
#define MFMA32(a,b,c) __builtin_amdgcn_mfma_f32_32x32x16_bf16(a,b,c,0,0,0)

static constexpr int Bb = 4, Nn = 2048, Hh = 4;
// SS2 = SCALE^0.5 * sqrt(log2(e)) so that S' = S * log2(e); exp2(S') = e^S
static constexpr float SS2 = 0.4246609001440095f;

__device__ __forceinline__ void lds16(const bf16* src, bf16* dst) {
  __builtin_amdgcn_global_load_lds(
      (const __attribute__((address_space(1))) void*)src,
      (__attribute__((address_space(3))) void*)dst, 16, 0, 0);
}

__device__ __forceinline__ f32x16 zero16() {
  f32x16 t;
#pragma unroll
  for (int i = 0; i < 16; ++i) t[i] = 0.f;
  return t;
}

// ---------------- prep: LDS-tiled coalesced transposes + copies + x->bf16 ----------------
// blocks 0..127   : 64x64 f32->bf16 transposes (coalesced loads AND stores)
// blocks 128..223 : wout_b copy + bias/zero pad rows
// blocks 224..4319: x -> bf16 conversion
__global__ __launch_bounds__(256) void prep_k(
    const float* Wqk, const float* Wv, const float* Wout, const float* bout,
    const float* Wf1, const float* Wf2, const float* x0, const float* x1,
    bf16* wqkv_t, bf16* wout_b, bf16* wfold_t, bf16* wf1b_t, bf16* wf2_t,
    bf16* xb0, bf16* xb1) {
  const int bid = blockIdx.x, tid = threadIdx.x;
  if (bid < 128) {
    __shared__ float LT[64][65];
    const float* src; bf16* dst;
    int srcLD, dstLD, r0, c0, rbase;
    int t = bid;
    if (t < 16) {            // Wqk[k][n] -> wqkv_t[n][k], rows 0-255
      src = Wqk; srcLD = 256; r0 = (t >> 2) * 64; c0 = (t & 3) * 64;
      dst = wqkv_t; dstLD = 256; rbase = 0;
    } else if (t < 32) { t -= 16;   // Wv -> wqkv_t rows 256-511
      src = Wv; srcLD = 256; r0 = (t >> 2) * 64; c0 = (t & 3) * 64;
      dst = wqkv_t + 256 * 256; dstLD = 256; rbase = 0;
    } else if (t < 64) { t -= 32;   // Wf1[k<256][o] -> wfold_t[o][k]
      src = Wf1; srcLD = 512; r0 = (t >> 3) * 64; c0 = (t & 7) * 64;
      dst = wfold_t; dstLD = 512; rbase = 0;
    } else if (t < 96) { t -= 64;   // Wf1[256+k2][o] -> wf1b_t[o][k2]
      src = Wf1; srcLD = 512; r0 = 256 + (t >> 3) * 64; c0 = (t & 7) * 64;
      dst = wf1b_t; dstLD = 256; rbase = 256;
    } else { t -= 96;               // Wf2[k][n] -> wf2_t[n][k]
      src = Wf2; srcLD = 256; r0 = (t >> 2) * 64; c0 = (t & 3) * 64;
      dst = wf2_t; dstLD = 512; rbase = 0;
    }
#pragma unroll
    for (int i = 0; i < 4; ++i) {
      int rr = (tid >> 4) + i * 16;
      int cc = (tid & 15) * 4;
      f32x4 v = *reinterpret_cast<const f32x4*>(&src[(size_t)(r0 + rr) * srcLD + c0 + cc]);
      LT[rr][cc] = v[0]; LT[rr][cc + 1] = v[1]; LT[rr][cc + 2] = v[2]; LT[rr][cc + 3] = v[3];
    }
    __syncthreads();
    int n = tid >> 2, kc = (tid & 3) * 16;
    bf16x8 o0, o1;
#pragma unroll
    for (int i = 0; i < 8; ++i) o0[i] = (bf16)LT[kc + i][n];
#pragma unroll
    for (int i = 0; i < 8; ++i) o1[i] = (bf16)LT[kc + 8 + i][n];
    bf16* dp = dst + (size_t)(c0 + n) * dstLD + (r0 - rbase) + kc;
    *reinterpret_cast<bf16x8*>(dp) = o0;
    *reinterpret_cast<bf16x8*>(dp + 8) = o1;
    return;
  }
  int id = bid - 128;
  if (id < 96) {           // wout_b: rows<256 = Wout copy; row 256 = bout; rest 0
    int base = id * 1024 + tid * 4;
#pragma unroll
    for (int i = 0; i < 4; ++i) {
      int e = base + i;
      if (e < 65536) wout_b[e] = (bf16)Wout[e];
      else { int id3 = e - 65536; int r = id3 >> 8, k = id3 & 255;
             wout_b[e] = (r == 0) ? (bf16)bout[k] : (bf16)0.f; }
    }
    return;
  }
  id -= 96;
  if (id < 4096) {         // x -> bf16, 4 f32 per thread
    int j = id * 256 + tid;
    const float* xs = (j < 524288) ? x0 : x1;
    bf16* xd = (j < 524288) ? xb0 : xb1;
    int jj = (j < 524288) ? j : j - 524288;
    f32x4 v = *reinterpret_cast<const f32x4*>(&xs[(size_t)jj * 4]);
    bf16x4 o; o[0] = (bf16)v[0]; o[1] = (bf16)v[1]; o[2] = (bf16)v[2]; o[3] = (bf16)v[3];
    *reinterpret_cast<bf16x4*>(&xd[(size_t)jj * 4]) = o;
  }
}

// ---------------- merged QKV projection + weight-fold GEMM (R16, unchanged) ----------------
__global__ __launch_bounds__(256, 2) void qkvfold_k(
    const bf16* xb0, const bf16* xb1, const bf16* wqkv_t,
    const float* bqk, const float* bv,
    bf16* qks0, bf16* qks1, bf16* vT0, bf16* vT1,
    const bf16* wout_b, const bf16* wf1b_t, const float* bf1,
    bf16* wfold_t, float* bfold) {
  const int fid = blockIdx.x;
  const bool fold = fid >= 512;
  int bx, by, bz;
  if (!fold) {
    bx = ((fid & 7) << 3) + ((fid >> 3) & 7);
    by = (fid >> 6) & 3;
    bz = fid >> 8;
  } else {
    int id = fid - 512;
    bx = id % 3; by = id / 3; bz = 0;
  }

  const bf16* Aa = fold ? wout_b : (bz ? xb1 : xb0);
  const bf16* Wt = fold ? wf1b_t : wqkv_t;

  const int tid = threadIdx.x;
  const int lane = tid & 63;
  const int w = tid >> 6;
  const int wr = w >> 1, wc = w & 1;
  const int m0r = bx * 128;
  const int n0 = by * 128;
  const int r15 = lane & 15, g = lane >> 4, rb = r15 & 7;
  const int l3 = lane >> 3, l7 = lane & 7;
  const int swzc = (l7 ^ l3) * 8;

  __shared__ bf16 At[2][8192];
  __shared__ bf16 Bt[2][8192];

  const bf16* aA = Aa + (size_t)(m0r + w*32 + l3) * 256 + swzc;
  const bf16* bB = Wt + (size_t)(n0 + w*32 + l3) * 256 + swzc;
  const int adst = (w*32) * 64;

  auto stage = [&](int buf, int kc) {
#pragma unroll
    for (int i = 0; i < 4; i++)
      lds16(aA + kc*64 + (size_t)i * 8 * 256, &At[buf][adst + i*512]);
#pragma unroll
    for (int i = 0; i < 4; i++)
      lds16(bB + kc*64 + (size_t)i * 8 * 256, &Bt[buf][adst + i*512]);
  };

  f32x4 acc[4][4];
#pragma unroll
  for (int i = 0; i < 4; i++)
#pragma unroll
    for (int j = 0; j < 4; j++) acc[i][j] = f32x4{0.f, 0.f, 0.f, 0.f};

  const int rx0 = ((0*4 + g) ^ rb) << 4;
  const int rx1 = ((1*4 + g) ^ rb) << 4;

  auto compute = [&](int cur) {
    const char* Ap = (const char*)&At[cur][0];
    const char* Bp = (const char*)&Bt[cur][0];
    __builtin_amdgcn_s_setprio(1);
#pragma unroll
    for (int ks = 0; ks < 2; ++ks) {
      const int rx = ks ? rx1 : rx0;
      bf16x8 af[4], bfr[4];
#pragma unroll
      for (int mf = 0; mf < 4; ++mf)
        af[mf] = *reinterpret_cast<const bf16x8*>(Ap + (wr*64 + mf*16 + r15) * 128 + rx);
#pragma unroll
      for (int nf = 0; nf < 4; ++nf)
        bfr[nf] = *reinterpret_cast<const bf16x8*>(Bp + (wc*64 + nf*16 + r15) * 128 + rx);
#pragma unroll
      for (int mf = 0; mf < 4; ++mf)
#pragma unroll
        for (int nf = 0; nf < 4; ++nf)
          acc[mf][nf] = MFMA(af[mf], bfr[nf], acc[mf][nf]);
    }
    __builtin_amdgcn_s_setprio(0);
  };

  stage(0, 0);
  int cur = 0;
  for (int kc = 0; kc < 3; ++kc) {
    stage(cur ^ 1, kc + 1);
    asm volatile("s_waitcnt vmcnt(8)" ::: "memory");
    __builtin_amdgcn_sched_barrier(0);
    __builtin_amdgcn_s_barrier();
    __builtin_amdgcn_sched_barrier(0);
    compute(cur);
    asm volatile("s_waitcnt lgkmcnt(0)" ::: "memory");
    __builtin_amdgcn_sched_barrier(0);
    __builtin_amdgcn_s_barrier();
    __builtin_amdgcn_sched_barrier(0);
    cur ^= 1;
  }
  asm volatile("s_waitcnt vmcnt(0)" ::: "memory");
  __builtin_amdgcn_sched_barrier(0);
  __builtin_amdgcn_s_barrier();
  __builtin_amdgcn_sched_barrier(0);
  compute(cur);

  if (!fold) {
    bf16* qks = bz ? qks1 : qks0;
    bf16* vT  = bz ? vT1  : vT0;
    if (by < 2) {
      // ---- Q path ----
#pragma unroll
      for (int mf = 0; mf < 4; ++mf)
#pragma unroll
        for (int nf = 0; nf < 4; ++nf) {
          f32x4 c = acc[mf][nf];
          int cg = n0 + wc*64 + nf*16 + r15;
#pragma unroll
          for (int r = 0; r < 4; ++r) {
            int rg = m0r + wr*64 + mf*16 + g*4 + r;
            int b = rg >> 11, n = rg & 2047;
            float val = (c[r] + bqk[cg]) * SS2;
            int h = cg >> 6, dh = cg & 63;
            qks[(((size_t)(b*Hh + h)) * Nn + n) * 64 + dh] = (bf16)val;
          }
        }
    } else {
      // ---- V path: LDS transpose (swizzled) + coalesced store along n ----
      __syncthreads();
      char* T = (char*)&At[0][0];
#pragma unroll
      for (int mf = 0; mf < 4; ++mf)
#pragma unroll
        for (int nf = 0; nf < 4; ++nf) {
          f32x4 c = acc[mf][nf];
          int cl = wc*64 + nf*16 + r15;
          float bvv = bv[(by - 2) * 128 + cl];
          int rl = wr*64 + mf*16 + g*4;
          bf16x4 o;
          o[0] = (bf16)(c[0] + bvv); o[1] = (bf16)(c[1] + bvv);
          o[2] = (bf16)(c[2] + bvv); o[3] = (bf16)(c[3] + bvv);
          int boff = cl*256 + ((rl*2) ^ ((cl & 15) << 4));
          *reinterpret_cast<bf16x4*>(T + boff) = o;
        }
      __syncthreads();
      const int cl = tid >> 1, nh = tid & 1;
      const int c2 = (by - 2) * 128 + cl;
      const int h = c2 >> 6, dh = c2 & 63;
      const int b = m0r >> 11, nbase = (m0r & 2047) + nh*64;
      bf16* dst = vT + (((size_t)(b*Hh + h)) * 64 + dh) * 2048 + nbase;
#pragma unroll
      for (int i = 0; i < 8; ++i) {
        int nl = nh*64 + i*8;
        int boff = cl*256 + ((nl*2) ^ ((cl & 15) << 4));
        *reinterpret_cast<uint4*>(dst + i*8) = *reinterpret_cast<const uint4*>(T + boff);
      }
    }
  } else {
#pragma unroll
    for (int mf = 0; mf < 4; ++mf)
#pragma unroll
      for (int nf = 0; nf < 4; ++nf) {
        f32x4 c = acc[mf][nf];
        int cg = n0 + wc*64 + nf*16 + r15;
#pragma unroll
        for (int r = 0; r < 4; ++r) {
          int rg = m0r + wr*64 + mf*16 + g*4 + r;
          if (rg < 256) wfold_t[(size_t)cg * 512 + 256 + rg] = (bf16)c[r];
          else if (rg == 256) bfold[cg] = c[r] + bf1[cg];
        }
      }
  }
}

// ---------------- pipelined MFMA GEMM, 128xBN tile, BK=64, dbuf + lds16 (R16) ----------------
template<int MODE, int BN, int MINW, int REMAP>
__global__ __launch_bounds__(256, MINW) void gemm_k(
    const bf16* Aa0, const bf16* Aa1, const bf16* Ac0, const bf16* Ac1,
    const bf16* Wt, const float* bias,
    bf16* ob0, bf16* ob1, float* of0, float* of1) {
  constexpr int KD  = 512;
  constexpr int LDA = (MODE == 4) ? 512 : 256;
  constexpr int NKC = KD / 64;
  constexpr int NF  = BN / 32;

  int bx = blockIdx.x, by = blockIdx.y, bz = blockIdx.z;
  if constexpr (REMAP == 1) {
    int id = blockIdx.x + 64 * (blockIdx.y + 4 * blockIdx.z);
    bx = ((id & 7) << 3) + ((id >> 3) & 7);
    by = (id >> 6) & 3;
    bz = id >> 8;
  }

  const bf16* Aa = bz ? Aa1 : Aa0;
  const bf16* Ac = bz ? Ac1 : Ac0;
  bf16*  ob = bz ? ob1 : ob0;
  float* of = bz ? of1 : of0;

  const int tid = threadIdx.x;
  const int lane = tid & 63;
  const int w = tid >> 6;
  const int wr = w >> 1, wc = w & 1;
  const int m0r = bx * 128;
  const int n0 = by * BN;
  const int r15 = lane & 15, g = lane >> 4, rb = r15 & 7;
  const int l3 = lane >> 3, l7 = lane & 7;
  const int swzc = (l7 ^ l3) * 8;

  __shared__ bf16 At[2][8192];
  __shared__ bf16 Bt[2][BN * 64];

  const bf16* aA = Aa + (size_t)(m0r + w*32 + l3) * LDA + swzc;
  const bf16* aC = (MODE == 3) ? (Ac + (size_t)(m0r + w*32 + l3) * 256 + swzc) : nullptr;
  const bf16* bB = Wt + (size_t)(n0 + w*(BN/4) + l3) * KD + swzc;
  const int adst = (w*32) * 64;
  const int bdst = (w*(BN/4)) * 64;

  auto stage = [&](int buf, int kc) {
    const bf16* ab; int kcol;
    if constexpr (MODE == 3) {
      if (kc < 4) { ab = aA; kcol = kc * 64; } else { ab = aC; kcol = (kc - 4) * 64; }
    } else { ab = aA; kcol = kc * 64; }
#pragma unroll
    for (int i = 0; i < 4; i++)
      lds16(ab + kcol + (size_t)i * 8 * LDA, &At[buf][adst + i*512]);
#pragma unroll
    for (int i = 0; i < NF; i++)
      lds16(bB + kc*64 + (size_t)i * 8 * KD, &Bt[buf][bdst + i*512]);
  };

  f32x4 acc[4][NF];
#pragma unroll
  for (int i = 0; i < 4; i++)
#pragma unroll
    for (int j = 0; j < NF; j++) acc[i][j] = f32x4{0.f, 0.f, 0.f, 0.f};

  const int rx0 = ((0*4 + g) ^ rb) << 4;
  const int rx1 = ((1*4 + g) ^ rb) << 4;

  auto compute = [&](int cur) {
    const char* Ap = (const char*)&At[cur][0];
    const char* Bp = (const char*)&Bt[cur][0];
    __builtin_amdgcn_s_setprio(1);
#pragma unroll
    for (int ks = 0; ks < 2; ++ks) {
      const int rx = ks ? rx1 : rx0;
      bf16x8 af[4], bfr[NF];
#pragma unroll
      for (int mf = 0; mf < 4; ++mf)
        af[mf] = *reinterpret_cast<const bf16x8*>(Ap + (wr*64 + mf*16 + r15) * 128 + rx);
#pragma unroll
      for (int nf = 0; nf < NF; ++nf)
        bfr[nf] = *reinterpret_cast<const bf16x8*>(Bp + (wc*(BN/2) + nf*16 + r15) * 128 + rx);
#pragma unroll
      for (int mf = 0; mf < 4; ++mf)
#pragma unroll
        for (int nf = 0; nf < NF; ++nf)
          acc[mf][nf] = MFMA(af[mf], bfr[nf], acc[mf][nf]);
    }
    __builtin_amdgcn_s_setprio(0);
  };

  stage(0, 0);
  int cur = 0;
  for (int kc = 0; kc < NKC - 1; ++kc) {
    stage(cur ^ 1, kc + 1);
    if constexpr (NF == 4) asm volatile("s_waitcnt vmcnt(8)" ::: "memory");
    else                   asm volatile("s_waitcnt vmcnt(6)" ::: "memory");
    __builtin_amdgcn_sched_barrier(0);
    __builtin_amdgcn_s_barrier();
    __builtin_amdgcn_sched_barrier(0);
    compute(cur);
    asm volatile("s_waitcnt lgkmcnt(0)" ::: "memory");
    __builtin_amdgcn_sched_barrier(0);
    __builtin_amdgcn_s_barrier();
    __builtin_amdgcn_sched_barrier(0);
    cur ^= 1;
  }
  asm volatile("s_waitcnt vmcnt(0)" ::: "memory");
  __builtin_amdgcn_sched_barrier(0);
  __builtin_amdgcn_s_barrier();
  __builtin_amdgcn_sched_barrier(0);
  compute(cur);

#pragma unroll
  for (int mf = 0; mf < 4; ++mf)
#pragma unroll
    for (int nf = 0; nf < NF; ++nf) {
      f32x4 c = acc[mf][nf];
      int cg = n0 + wc*(BN/2) + nf*16 + r15;
#pragma unroll
      for (int r = 0; r < 4; ++r) {
        int rg = m0r + wr*64 + mf*16 + g*4 + r;
        if constexpr (MODE == 3) {
          ob[(size_t)rg * 512 + cg] = (bf16)(c[r] + bias[cg]);
        } else {   // MODE 4
          of[(size_t)rg * 256 + cg] = c[r] + bias[cg] + (float)Ac[(size_t)rg * 256 + cg];
        }
      }
    }
}

// ---------------- fused dual-direction attention: j-SPLIT wave pairs (R16, unchanged) ----------------
__global__ __launch_bounds__(512, 4) void attn_k(
    const bf16* qks0, const bf16* qks1, const bf16* vT0, const bf16* vT1,
    bf16* m0o, bf16* m1o) {
  const int B = blockIdx.x + 16 * (blockIdx.y + 16 * blockIdx.z);
  const int xcd = B & 7, kk = B >> 3;
  const int group = 4 * xcd + (kk >> 4);
  const int it = kk & 15;
  const int bh = group & 15, dir = group >> 4;

  const bf16* Q  = (dir ? qks1 : qks0) + (size_t)bh * (Nn * 64);
  const bf16* Kp = (dir ? qks0 : qks1) + (size_t)bh * (Nn * 64);
  const bf16* Vp = (dir ? vT0  : vT1 ) + (size_t)bh * (64 * Nn);
  bf16* out = dir ? m1o : m0o;
  const int b = bh >> 2, h = bh & 3;

  const int tid = threadIdx.x, lane = tid & 63, w = tid >> 6;
  const int ig = w >> 1, hj = w & 1;
  const int l31 = lane & 31, hi = lane >> 5, xr = l31 & 7;
  const int iw = it * 128 + ig * 32;

  __shared__ char smem[65536];
  bf16* KV = (bf16*)smem;
  const int kbase = hj * 8192;
  const int vbase = 16384 + hj * 8192;

  bf16x8 qf[4];
#pragma unroll
  for (int kt = 0; kt < 4; ++kt)
    qf[kt] = *reinterpret_cast<const bf16x8*>(
        &Q[(size_t)(iw + l31) * 64 + kt*16 + hi*8]);

  f32x16 acc[2]; acc[0] = zero16(); acc[1] = zero16();
  float rsum = 0.f;

  const int l3 = lane >> 3, l7 = lane & 7;
  const int swz = ((l7 ^ l3) * 8);
  const bf16* ks0 = Kp + (size_t)(ig*16 +     l3) * 64 + swz;
  const bf16* ks1 = Kp + (size_t)(ig*16 + 8 + l3) * 64 + swz;
  const bf16* vs0 = Vp + (size_t)(ig*16 +     l3) * 2048 + swz;
  const bf16* vs1 = Vp + (size_t)(ig*16 + 8 + l3) * 2048 + swz;
  const int kd0 = (ig*16    ) * 64;
  const int kd1 = (ig*16 + 8) * 64;

  auto stage = [&](int buf, int j0) {
    lds16(ks0 + (size_t)j0 * 64, KV + kbase + buf*4096 + kd0);
    lds16(ks1 + (size_t)j0 * 64, KV + kbase + buf*4096 + kd1);
    lds16(vs0 + j0,              KV + vbase + buf*4096 + kd0);
    lds16(vs1 + j0,              KV + vbase + buf*4096 + kd1);
  };

  int kby[2][4], vby[2][4];
#pragma unroll
  for (int jm = 0; jm < 2; ++jm)
#pragma unroll
    for (int kt = 0; kt < 4; ++kt)
      kby[jm][kt] = (jm*32 + l31) * 128 + (((2*kt + hi) ^ xr) << 4);
#pragma unroll
  for (int nt = 0; nt < 2; ++nt)
#pragma unroll
    for (int gg = 0; gg < 4; ++gg)
      vby[nt][gg] = (nt*32 + l31) * 128 + (((2*gg + hi) ^ xr) << 4);

  auto compute_tile = [&](int cur) {
    const char* Kb = (const char*)(KV + kbase + cur*4096);
    const char* Vb = (const char*)(KV + vbase + cur*4096);
    f32x16 st[2];
    __builtin_amdgcn_s_setprio(1);
#pragma unroll
    for (int jm = 0; jm < 2; ++jm) {
      f32x16 t = zero16();
#pragma unroll
      for (int kt = 0; kt < 4; ++kt) {
        bf16x8 kf = *reinterpret_cast<const bf16x8*>(Kb + kby[jm][kt]);
        t = MFMA32(kf, qf[kt], t);
      }
      st[jm] = t;
    }
    __builtin_amdgcn_s_setprio(0);
    bf16x8 pa[4];
#pragma unroll
    for (int jm = 0; jm < 2; ++jm) {
      unsigned dw[8];
#pragma unroll
      for (int s = 0; s < 8; ++s) {
        float e0 = __builtin_amdgcn_exp2f(st[jm][2*s]);
        float e1 = __builtin_amdgcn_exp2f(st[jm][2*s + 1]);
        rsum += e0 + e1;
        asm("v_cvt_pk_bf16_f32 %0, %1, %2" : "=v"(dw[s]) : "v"(e0), "v"(e1));
      }
#pragma unroll
      for (int kt2 = 0; kt2 < 2; ++kt2) {
        unsigned a0 = dw[4*kt2 + 0], b0 = dw[4*kt2 + 2];
        unsigned a1 = dw[4*kt2 + 1], b1 = dw[4*kt2 + 3];
        asm volatile("v_permlane32_swap_b32 %0, %1" : "+v"(a0), "+v"(b0));
        asm volatile("v_permlane32_swap_b32 %0, %1" : "+v"(a1), "+v"(b1));
        u32x4 uu; uu[0] = a0; uu[1] = a1; uu[2] = b0; uu[3] = b1;
        pa[jm*2 + kt2] = __builtin_bit_cast(bf16x8, uu);
      }
    }
    __builtin_amdgcn_s_setprio(1);
#pragma unroll
    for (int gg = 0; gg < 4; ++gg) {
#pragma unroll
      for (int nt = 0; nt < 2; ++nt) {
        bf16x8 vf = *reinterpret_cast<const bf16x8*>(Vb + vby[nt][gg]);
        acc[nt] = MFMA32(pa[gg], vf, acc[nt]);
      }
    }
    __builtin_amdgcn_s_setprio(0);
  };

  const int jt0 = hj << 4;
  stage(0, jt0 << 6);
  int cur = 0;
  for (int t = 0; t < 15; ++t) {
    stage(cur ^ 1, (jt0 + t + 1) << 6);
    asm volatile("s_waitcnt vmcnt(4)" ::: "memory");
    __builtin_amdgcn_s_barrier();
    compute_tile(cur);
    asm volatile("s_waitcnt lgkmcnt(0)" ::: "memory");
    __builtin_amdgcn_s_barrier();
    cur ^= 1;
  }
  asm volatile("s_waitcnt vmcnt(0)" ::: "memory");
  __builtin_amdgcn_s_barrier();
  compute_tile(cur);

  rsum += __shfl_xor(rsum, 32);
  __syncthreads();
  float* Ex = (float*)smem;
  if (hj == 1) {
#pragma unroll
    for (int nt = 0; nt < 2; ++nt)
#pragma unroll
      for (int r = 0; r < 16; ++r)
        Ex[(ig*33 + nt*16 + r) * 64 + lane] = acc[nt][r];
    Ex[(ig*33 + 32) * 64 + lane] = rsum;
  }
  __syncthreads();
  if (hj == 0) {
    float tot = rsum + Ex[(ig*33 + 32) * 64 + lane];
    float* Rt2 = (float*)(smem + 49152);
    if (lane < 32) Rt2[ig*32 + l31] = tot;
    f32x4 rv[4];
#pragma unroll
    for (int q = 0; q < 4; ++q)
      rv[q] = *reinterpret_cast<const f32x4*>(&Rt2[ig*32 + 8*q + 4*hi]);
#pragma unroll
    for (int r = 0; r < 16; ++r) {
      float inv = 1.0f / rv[r >> 2][r & 3];
      int row = iw + (r & 3) + 8*(r >> 2) + 4*hi;
#pragma unroll
      for (int nt = 0; nt < 2; ++nt) {
        float o = acc[nt][r] + Ex[(ig*33 + nt*16 + r) * 64 + lane];
        int col = h*64 + nt*32 + l31;
        out[((size_t)b * Nn + row) * 256 + col] = (bf16)(o * inv);
      }
    }
  }
}

// ---------------- LayerNorm + exact GELU: one wave per 512-col row (R16) ----------------
__global__ __launch_bounds__(256) void ln_gelu_k(
    bf16* hg, const float* g, const float* bb) {
  const int row = (blockIdx.x << 2) + (threadIdx.x >> 6);
  const int lane = threadIdx.x & 63;
  bf16* hr = hg + (size_t)row * 512 + lane * 8;
  bf16x8 v = *reinterpret_cast<const bf16x8*>(hr);
  float f[8];
  float s = 0.f, sq = 0.f;
#pragma unroll
  for (int i = 0; i < 8; ++i) { f[i] = (float)v[i]; s += f[i]; sq += f[i]*f[i]; }
#pragma unroll
  for (int m = 1; m < 64; m <<= 1) { s += __shfl_xor(s, m); sq += __shfl_xor(sq, m); }
  float mu = s * (1.f / 512.f);
  float var = sq * (1.f / 512.f) - mu * mu;
  float rsv = rsqrtf(var + 1e-5f);
  f32x4 g0 = *reinterpret_cast<const f32x4*>(&g[lane*8]);
  f32x4 g1 = *reinterpret_cast<const f32x4*>(&g[lane*8 + 4]);
  f32x4 b0 = *reinterpret_cast<const f32x4*>(&bb[lane*8]);
  f32x4 b1 = *reinterpret_cast<const f32x4*>(&bb[lane*8 + 4]);
  bf16x8 o;
#pragma unroll
  for (int i = 0; i < 8; ++i) {
    float gv = (i < 4) ? g0[i] : g1[i-4];
    float bv = (i < 4) ? b0[i] : b1[i-4];
    float xn = (f[i] - mu) * rsv * gv + bv;
    float ge = 0.5f * xn * (1.f + erff(xn * 0.70710678118f));
    o[i] = (bf16)ge;
  }
  *reinterpret_cast<bf16x8*>(hr) = o;
}

extern "C" void kernel_launch(void* const* d_in, const int* in_sizes, int n_in,
                              void* d_out, int out_size, void* d_ws, size_t ws_size,
                              hipStream_t stream) {
  (void)in_sizes; (void)n_in; (void)out_size; (void)ws_size;
  const float* x0   = (const float*)d_in[0];
  const float* x1   = (const float*)d_in[1];
  const float* Wqk  = (const float*)d_in[2];
  const float* bqk  = (const float*)d_in[3];
  const float* Wv   = (const float*)d_in[4];
  const float* bv   = (const float*)d_in[5];
  const float* Wout = (const float*)d_in[6];
  const float* bout = (const float*)d_in[7];
  const float* Wf1  = (const float*)d_in[8];
  const float* bf1  = (const float*)d_in[9];
  const float* ln_g = (const float*)d_in[10];
  const float* ln_b = (const float*)d_in[11];
  const float* Wf2  = (const float*)d_in[12];
  const float* bf2  = (const float*)d_in[13];
  float* y = (float*)d_out;

  bf16* p = (bf16*)d_ws;
  bf16* wqkv_t = p; p += 131072;
  bf16* wout_b = p; p += 98304;
  bf16* wfold_t = p; p += 262144;
  bf16* wf1b_t = p; p += 131072;
  bf16* wf2_t  = p; p += 131072;
  float* bfold = (float*)p; p += 1024;     // 512 f32
  bf16* xb0  = p; p += 2097152;
  bf16* xb1  = p; p += 2097152;
  bf16* qks0 = p; p += 2097152;
  bf16* qks1 = p; p += 2097152;
  bf16* vT0  = p; p += 2097152;
  bf16* vT1  = p; p += 2097152;
  bf16* m0   = p; p += 2097152;
  bf16* m1   = p; p += 2097152;
  bf16* hg0  = p; p += 4194304;
  bf16* hg1  = p; p += 4194304;

  dim3 blk(256);
  prep_k<<<4320, blk, 0, stream>>>(Wqk, Wv, Wout, bout, Wf1, Wf2, x0, x1,
                                   wqkv_t, wout_b, wfold_t, wf1b_t, wf2_t, xb0, xb1);
  qkvfold_k<<<dim3(524), blk, 0, stream>>>(
      xb0, xb1, wqkv_t, bqk, bv, qks0, qks1, vT0, vT1,
      wout_b, wf1b_t, bf1, wfold_t, bfold);
  attn_k<<<dim3(16, 16, 2), dim3(512), 0, stream>>>(qks0, qks1, vT0, vT1, m0, m1);
  gemm_k<3,128,2,1><<<dim3(64, 4, 2), blk, 0, stream>>>(
      xb0, xb1, m0, m1, wfold_t, bfold,
      hg0, hg1, nullptr, nullptr);
  ln_gelu_k<<<dim3(4096), blk, 0, stream>>>(hg0, ln_g, ln_b);
  gemm_k<4,64,3,0><<<dim3(64, 4, 2), blk, 0, stream>>>(
      hg0, hg1, xb0, xb1, wf2_t, bf2,
      nullptr, nullptr, y, y + 2097152);
}